// Round 2
// baseline (347.102 us; speedup 1.0000x reference)
//
#include <hip/hip_runtime.h>
#include <math.h>

#define Dd 256
#define Nn 4096
#define Bb 4
#define BQ 64       // q rows per attn block (4 waves x 16 in S phase)
#define BK 64       // kv rows per tile

typedef _Float16 f16;
typedef _Float16 half8 __attribute__((ext_vector_type(8)));
typedef _Float16 half4 __attribute__((ext_vector_type(4)));
typedef float f32x4 __attribute__((ext_vector_type(4)));

#define LOG2E 1.4426950408889634f

// DPP row_ror butterfly over 16-lane rows (VALU pipe, not LDS)
template <int CTRL>
__device__ __forceinline__ float dppf(float x) {
    int r = __builtin_amdgcn_update_dpp(0, __builtin_bit_cast(int, x),
                                        CTRL, 0xF, 0xF, false);
    return __builtin_bit_cast(float, r);
}
__device__ __forceinline__ float red16_max(float x) {
    x = fmaxf(x, dppf<0x128>(x));
    x = fmaxf(x, dppf<0x124>(x));
    x = fmaxf(x, dppf<0x122>(x));
    x = fmaxf(x, dppf<0x121>(x));
    return x;
}
__device__ __forceinline__ float red16_sum(float x) {
    x += dppf<0x128>(x); x += dppf<0x124>(x);
    x += dppf<0x122>(x); x += dppf<0x121>(x);
    return x;
}

// ---------------------------------------------------------------------------
// Kernel 0: W transpose+cast.  Wt[which][d'][d] = (f16) W[d][d']
// ---------------------------------------------------------------------------
__global__ __launch_bounds__(256) void wtrans(
    const float* __restrict__ Wq, const float* __restrict__ Wk,
    const float* __restrict__ Wv, f16* __restrict__ Wt)
{
    __shared__ float ld[64][65];
    const int which = blockIdx.y;
    const float* W = which == 0 ? Wq : (which == 1 ? Wk : Wv);
    const int tr = (blockIdx.x >> 2) * 64;
    const int tc = (blockIdx.x & 3) * 64;
    const int t = threadIdx.x;
    #pragma unroll
    for (int i = 0; i < 16; ++i) {
        int u = t + i * 256, r = u >> 6, c = u & 63;
        ld[r][c] = W[(size_t)(tr + r) * Dd + tc + c];
    }
    __syncthreads();
    f16* Wo = Wt + (size_t)which * Dd * Dd;
    #pragma unroll
    for (int i = 0; i < 16; ++i) {
        int u = t + i * 256, cp = u >> 6, rp = u & 63;
        Wo[(size_t)(tc + cp) * Dd + tr + rp] = (f16)ld[rp][cp];
    }
}

// ---------------------------------------------------------------------------
// Kernel 1: FUSED QKV projection via MFMA (unchanged).
// ---------------------------------------------------------------------------
__global__ __launch_bounds__(512, 1) void qkv_fused(
    const float* __restrict__ x, const f16* __restrict__ Wt,
    const float* __restrict__ bq, const float* __restrict__ bk,
    const float* __restrict__ bv,
    f16* __restrict__ Qh, f16* __restrict__ Kh, f16* __restrict__ Vth)
{
    __shared__ __align__(16) f16 Ws[256][264];   // 135168 B; first 64 rows alias xT
    __shared__ float bs3[3][256];                //   3072 B
    f16 (*xT)[264] = (f16 (*)[264])&Ws[0][0];    // xT[64][264]

    const int t = threadIdx.x;
    const int wave = t >> 6, lane = t & 63, quad = lane >> 4, l15 = lane & 15;
    const int g = wave & 3;        // row group: rows 16g..16g+16
    const int h = wave >> 2;       // col half: d' in [128h, 128h+128)
    const int n0 = blockIdx.x * 64;
    const int b = blockIdx.y;

    if (t < 256) { bs3[0][t] = bq[t]; bs3[1][t] = bk[t]; bs3[2][t] = bv[t]; }

    // Stage xT[n][d] = (f16) x[b][d][n0+n]; 512 threads x 8 float4 reads
    const float* xb = x + (size_t)b * Dd * Nn;
    #pragma unroll
    for (int i = 0; i < 8; ++i) {
        int u = t + i * 512, d = u >> 4, nq = (u & 15) * 4;
        float4 v4 = *(const float4*)&xb[(size_t)d * Nn + n0 + nq];
        xT[nq + 0][d] = (f16)v4.x; xT[nq + 1][d] = (f16)v4.y;
        xT[nq + 2][d] = (f16)v4.z; xT[nq + 3][d] = (f16)v4.w;
    }
    __syncthreads();

    // Lift A-fragments to registers (xT is dead after this + barrier)
    half8 a[8];
    #pragma unroll
    for (int c = 0; c < 8; ++c)
        a[c] = *(const half8*)&xT[16 * g + l15][c * 32 + quad * 8];

    const int nrow = n0 + 16 * g + quad * 4;

    for (int which = 0; which < 3; ++which) {
        __syncthreads();   // A-frag reads (which=0) / prior MFMA reads done

        // Bulk-stage full W^T (256x256 halfs) from L2: 16 b128 per thread
        const f16* Wb = Wt + (size_t)which * Dd * Dd;
        #pragma unroll
        for (int i = 0; i < 16; ++i) {
            int u = t + i * 512;
            int r = u >> 5, c = u & 31;
            *(half8*)&Ws[r][c * 8] = *(const half8*)(Wb + (size_t)r * Dd + c * 8);
        }
        __syncthreads();

        // 64 MFMAs/wave, zero barriers: this wave's 8 col-tiles x 8 k-chunks
        f32x4 acc[8];
        #pragma unroll
        for (int dt = 0; dt < 8; ++dt) acc[dt] = (f32x4){0.f, 0.f, 0.f, 0.f};
        #pragma unroll
        for (int c = 0; c < 8; ++c) {
            #pragma unroll
            for (int dt = 0; dt < 8; ++dt) {
                half8 bfr = *(const half8*)&Ws[h * 128 + dt * 16 + l15][c * 32 + quad * 8];
                acc[dt] = __builtin_amdgcn_mfma_f32_16x16x32_f16(a[c], bfr, acc[dt], 0, 0, 0);
            }
        }

        // Epilogue
        if (which < 2) {
            f16* O = (which == 0 ? Qh : Kh) + ((size_t)b * Nn + nrow) * Dd;
            #pragma unroll
            for (int dt = 0; dt < 8; ++dt) {
                int col = h * 128 + dt * 16 + l15;
                float bvv = bs3[which][col];
                #pragma unroll
                for (int r = 0; r < 4; ++r)
                    O[(size_t)r * Dd + col] = (f16)(acc[dt][r] + bvv);
            }
        } else {
            f16* O = Vth + (size_t)b * Dd * Nn;
            #pragma unroll
            for (int dt = 0; dt < 8; ++dt) {
                int col = h * 128 + dt * 16 + l15;
                float bvv = bs3[2][col];
                half4 o;
                #pragma unroll
                for (int r = 0; r < 4; ++r) o[r] = (f16)(acc[dt][r] + bvv);
                *(half4*)&O[(size_t)col * Nn + nrow] = o;
            }
        }
    }
}

// ---------------------------------------------------------------------------
// Kernel 2: MFMA flash attention, R15: 4-wave (256-thr) blocks, BQ=64, BK=64.
// R1 post-mortem: occupancy was register-capped (~116 VGPR + 64 AGPR acc
// ~ 180/512 unified -> 2 waves/SIMD -> exactly one 8-wave block/CU), so the
// LDS cut bought nothing. This version shrinks the scheduling quantum:
// 4-wave blocks place 1 wave/SIMD each, so at ~150-170 regs/wave the CU
// holds 2-3 INDEPENDENT blocks -> phases of different blocks overlap
// (one block's K-stage/softmax/barriers hide another's MFMAs).
// V loads issue right after the S-MFMAs (T14: L2 latency hides under the
// softmax VALU chain + 2 barriers). LDS 34.3 KB (Ps aliases Ks). split=4
// -> grid 1024 blocks fills 2-4 slots/CU with no tail.
// Wave w: S phase owns q rows [q0+16w, q0+16w+16); PV owns d [64w, 64w+64).
// ---------------------------------------------------------------------------
__global__ __launch_bounds__(256, 3) void attn_mfma(
    const f16* __restrict__ Qh, const f16* __restrict__ Kh,
    const f16* __restrict__ Vth, f16* __restrict__ Opart,
    float* __restrict__ mpart, float* __restrict__ lpart, int kvlen)
{
    __shared__ __align__(16) f16 Ks[BK][264];   // 33792 B  K[kv][d], pad 8
    __shared__ float alpha_s[4][16];            //   256 B
    __shared__ float l_sh[4][16];               //   256 B
    // Ps[4][16][72] (9216 B) aliases the front of Ks — K tile dead after
    // the S-phase MFMAs; Ps dead before the next K staging.
    f16 (*Ps)[16][72] = (f16 (*)[16][72])&Ks[0][0];

    const int t    = threadIdx.x;
    const int wave = t >> 6, lane = t & 63;
    const int quad = lane >> 4, l15 = lane & 15;
    const int b    = blockIdx.y;
    const int s    = blockIdx.z;
    const int q0   = blockIdx.x * BQ;
    const int qw   = q0 + wave * 16;       // this wave's S-phase q rows
    const int kv0  = s * kvlen;

    // Q A-fragments, pre-scaled by log2(e)
    half8 qf[8];
    const f16* Qrow = Qh + ((size_t)b * Nn + qw + l15) * Dd + quad * 8;
    #pragma unroll
    for (int c = 0; c < 8; ++c) {
        qf[c] = *(const half8*)(Qrow + c * 32);
        qf[c] = qf[c] * (f16)LOG2E;
    }

    // acc[qb*4+dt]: q-block qb (0..3), d-col = 64*wave + dt*16 + l15 (dt 0..3)
    f32x4 acc[16];
    #pragma unroll
    for (int n = 0; n < 16; ++n) acc[n] = (f32x4){0.f, 0.f, 0.f, 0.f};
    f32x4 m4 = {-1e30f, -1e30f, -1e30f, -1e30f};
    f32x4 l4 = {0.f, 0.f, 0.f, 0.f};

    const f16* Kb   = Kh + (size_t)b * Nn * Dd;
    const f16* Vrow = Vth + (size_t)b * Dd * Nn
                    + (size_t)(wave * 64 + l15) * Nn + quad * 8;

    for (int k0 = kv0; k0 < kv0 + kvlen; k0 += BK) {
        __syncthreads();   // A: prior PV readers of Ps (= Ks alias) done

        // Stage K tile: 64 rows x 512 B = 32 KB; 8 x b128 per thread
        #pragma unroll
        for (int i = 0; i < 8; ++i) {
            int u = t + i * 256;
            int r = u >> 5, c = u & 31;
            *(half8*)&Ks[r][c * 8] =
                *(const half8*)(Kb + (size_t)(k0 + r) * Dd + c * 8);
        }
        __syncthreads();   // B: K visible

        // S = Q K^T (log2 domain), four 16x16 col-blocks (kv 0..63)
        f32x4 S[4];
        #pragma unroll
        for (int cb = 0; cb < 4; ++cb) S[cb] = (f32x4){0.f, 0.f, 0.f, 0.f};
        #pragma unroll
        for (int c = 0; c < 8; ++c) {
            #pragma unroll
            for (int cb = 0; cb < 4; ++cb) {
                half8 kb = *(const half8*)&Ks[cb * 16 + l15][c * 32 + quad * 8];
                S[cb] = __builtin_amdgcn_mfma_f32_16x16x32_f16(qf[c], kb, S[cb], 0, 0, 0);
            }
        }

        // Issue V loads NOW (T14): 4 d-tiles x 2 kv-halves. Their first use
        // is PV, behind the softmax VALU chain + 2 barriers -> L2 latency
        // is fully hidden; short register lifetime.
        half8 vbf[4][2];
        #pragma unroll
        for (int dt = 0; dt < 4; ++dt) {
            #pragma unroll
            for (int cbb = 0; cbb < 2; ++cbb)
                vbf[dt][cbb] = *(const half8*)(Vrow + (size_t)dt * 16 * Nn + k0 + cbb * 32);
        }

        // Online softmax (exp2 domain), DPP reductions over 16 lanes
        f32x4 tmax = S[0];
        #pragma unroll
        for (int cb = 1; cb < 4; ++cb) {
            tmax.x = fmaxf(tmax.x, S[cb].x); tmax.y = fmaxf(tmax.y, S[cb].y);
            tmax.z = fmaxf(tmax.z, S[cb].z); tmax.w = fmaxf(tmax.w, S[cb].w);
        }
        tmax.x = red16_max(tmax.x); tmax.y = red16_max(tmax.y);
        tmax.z = red16_max(tmax.z); tmax.w = red16_max(tmax.w);
        f32x4 newm;
        newm.x = fmaxf(m4.x, tmax.x); newm.y = fmaxf(m4.y, tmax.y);
        newm.z = fmaxf(m4.z, tmax.z); newm.w = fmaxf(m4.w, tmax.w);
        f32x4 al;
        al.x = __builtin_amdgcn_exp2f(m4.x - newm.x);
        al.y = __builtin_amdgcn_exp2f(m4.y - newm.y);
        al.z = __builtin_amdgcn_exp2f(m4.z - newm.z);
        al.w = __builtin_amdgcn_exp2f(m4.w - newm.w);
        f32x4 P[4];
        #pragma unroll
        for (int cb = 0; cb < 4; ++cb) {
            P[cb].x = __builtin_amdgcn_exp2f(S[cb].x - newm.x);
            P[cb].y = __builtin_amdgcn_exp2f(S[cb].y - newm.y);
            P[cb].z = __builtin_amdgcn_exp2f(S[cb].z - newm.z);
            P[cb].w = __builtin_amdgcn_exp2f(S[cb].w - newm.w);
        }
        f32x4 rsum = P[0];
        #pragma unroll
        for (int cb = 1; cb < 4; ++cb) rsum += P[cb];
        rsum.x = red16_sum(rsum.x); rsum.y = red16_sum(rsum.y);
        rsum.z = red16_sum(rsum.z); rsum.w = red16_sum(rsum.w);
        l4 = l4 * al + rsum;
        m4 = newm;

        __syncthreads();   // B2: every wave's S-phase Ks reads done

        // Publish P (f16) and alpha into the Ks-alias region
        const int pr = quad * 4;
        #pragma unroll
        for (int cb = 0; cb < 4; ++cb) {
            Ps[wave][pr + 0][cb * 16 + l15] = (f16)P[cb].x;
            Ps[wave][pr + 1][cb * 16 + l15] = (f16)P[cb].y;
            Ps[wave][pr + 2][cb * 16 + l15] = (f16)P[cb].z;
            Ps[wave][pr + 3][cb * 16 + l15] = (f16)P[cb].w;
        }
        if (l15 == 0) {
            float4 a4 = {al.x, al.y, al.z, al.w};
            *(float4*)&alpha_s[wave][pr] = a4;
        }
        __syncthreads();   // C: Ps/alpha visible

        // Rescale O by each q-block's alpha (skip when converged)
        float4 alq[4];
        int need = 0;
        #pragma unroll
        for (int qb = 0; qb < 4; ++qb) {
            alq[qb] = *(const float4*)&alpha_s[qb][pr];
            need |= (alq[qb].x != 1.f) | (alq[qb].y != 1.f) |
                    (alq[qb].z != 1.f) | (alq[qb].w != 1.f);
        }
        if (__any(need)) {
            #pragma unroll
            for (int qb = 0; qb < 4; ++qb) {
                f32x4 a = {alq[qb].x, alq[qb].y, alq[qb].z, alq[qb].w};
                #pragma unroll
                for (int dt = 0; dt < 4; ++dt) acc[qb * 4 + dt] *= a;
            }
        }

        // PV: 4 q-blocks x 2 kv-halves x 4 d-tiles; A-frag one b128 each
        #pragma unroll
        for (int qb = 0; qb < 4; ++qb) {
            #pragma unroll
            for (int cbb = 0; cbb < 2; ++cbb) {
                half8 ap = *(const half8*)&Ps[qb][l15][cbb * 32 + quad * 8];
                #pragma unroll
                for (int dt = 0; dt < 4; ++dt)
                    acc[qb * 4 + dt] = __builtin_amdgcn_mfma_f32_16x16x32_f16(
                        ap, vbf[dt][cbb], acc[qb * 4 + dt], 0, 0, 0);
            }
        }
    }

    // Publish l, write m/l partials (this wave's own 16 q rows)
    __syncthreads();
    if (l15 == 0) {
        const int pr = quad * 4;
        float4 lv = {l4.x, l4.y, l4.z, l4.w};
        *(float4*)&l_sh[wave][pr] = lv;
        float mv[4] = {m4.x, m4.y, m4.z, m4.w};
        float lvv[4] = {l4.x, l4.y, l4.z, l4.w};
        #pragma unroll
        for (int r = 0; r < 4; ++r) {
            int n = qw + pr + r;
            mpart[(size_t)(s * Bb + b) * Nn + n] = mv[r];
            lpart[(size_t)(s * Bb + b) * Nn + n] = lvv[r];
        }
    }
    __syncthreads();

    // Normalize + store partial O: 4 q-blocks x this wave's 4 d-tiles
    f16* Ob = Opart + (size_t)(s * Bb + b) * Dd * Nn;
    #pragma unroll
    for (int qb = 0; qb < 4; ++qb) {
        float4 lq = *(const float4*)&l_sh[qb][quad * 4];
        f32x4 inv = {1.f / lq.x, 1.f / lq.y, 1.f / lq.z, 1.f / lq.w};
        #pragma unroll
        for (int dt = 0; dt < 4; ++dt) {
            int d = wave * 64 + dt * 16 + l15;
            f32x4 o = acc[qb * 4 + dt] * inv;
            half4 oh;
            oh[0] = (f16)o.x; oh[1] = (f16)o.y; oh[2] = (f16)o.z; oh[3] = (f16)o.w;
            *(half4*)&Ob[(size_t)d * Nn + q0 + qb * 16 + quad * 4] = oh;
        }
    }
}

// ---------------------------------------------------------------------------
// Kernel 3: combine split partials (exp2 domain). Templated on split count
// so all per-split arrays stay statically indexed (registers, not scratch).
// ---------------------------------------------------------------------------
template <int S>
__global__ __launch_bounds__(256) void combine(
    const f16* __restrict__ Opart, const float* __restrict__ mpart,
    const float* __restrict__ lpart, float* __restrict__ out)
{
    const int t = threadIdx.x;
    const int n0 = (blockIdx.x * 256 + t) * 8;
    const int d = blockIdx.y, b = blockIdx.z;

    float m[S][8], l[S][8];
    #pragma unroll
    for (int s = 0; s < S; ++s) {
        size_t base = (size_t)(s * Bb + b) * Nn + n0;
        float4 a0 = *(const float4*)&mpart[base];
        float4 a1 = *(const float4*)&mpart[base + 4];
        float4 c0 = *(const float4*)&lpart[base];
        float4 c1 = *(const float4*)&lpart[base + 4];
        m[s][0]=a0.x; m[s][1]=a0.y; m[s][2]=a0.z; m[s][3]=a0.w;
        m[s][4]=a1.x; m[s][5]=a1.y; m[s][6]=a1.z; m[s][7]=a1.w;
        l[s][0]=c0.x; l[s][1]=c0.y; l[s][2]=c0.z; l[s][3]=c0.w;
        l[s][4]=c1.x; l[s][5]=c1.y; l[s][6]=c1.z; l[s][7]=c1.w;
    }
    float w[S][8];
    #pragma unroll
    for (int jx = 0; jx < 8; ++jx) {
        float M = m[0][jx];
        #pragma unroll
        for (int s = 1; s < S; ++s) M = fmaxf(M, m[s][jx]);
        float L = 0.f;
        #pragma unroll
        for (int s = 0; s < S; ++s) {
            float ws = l[s][jx] * __builtin_amdgcn_exp2f(m[s][jx] - M);
            w[s][jx] = ws; L += ws;
        }
        float invL = 1.f / L;
        #pragma unroll
        for (int s = 0; s < S; ++s) w[s][jx] *= invL;
    }

    float o[8];
    #pragma unroll
    for (int jx = 0; jx < 8; ++jx) o[jx] = 0.f;
    #pragma unroll
    for (int s = 0; s < S; ++s) {
        half8 h = *(const half8*)&Opart[((size_t)(s * Bb + b) * Dd + d) * Nn + n0];
        #pragma unroll
        for (int jx = 0; jx < 8; ++jx) o[jx] += w[s][jx] * (float)h[jx];
    }
    float* op = out + ((size_t)b * Dd + d) * Nn + n0;
    f32x4 o0 = {o[0], o[1], o[2], o[3]};
    f32x4 o1 = {o[4], o[5], o[6], o[7]};
    *(f32x4*)op = o0;
    *(f32x4*)(op + 4) = o1;
}

extern "C" void kernel_launch(void* const* d_in, const int* in_sizes, int n_in,
                              void* d_out, int out_size, void* d_ws, size_t ws_size,
                              hipStream_t stream) {
    const float* x  = (const float*)d_in[0];
    const float* Wq = (const float*)d_in[1];
    const float* bq = (const float*)d_in[2];
    const float* Wk = (const float*)d_in[3];
    const float* bk = (const float*)d_in[4];
    const float* Wv = (const float*)d_in[5];
    const float* bv = (const float*)d_in[6];
    float* out = (float*)d_out;

    // split=4 -> (Nn/BQ=64) x 4 x 4 = 1024 attn blocks: fills 2-4 block
    // slots per CU with no tail. Fall back to split=2 if ws can't hold it.
    const size_t head = (size_t)3 * Bb * Nn * Dd * sizeof(f16)   // Qh,Kh,Vth
                      + (size_t)3 * Dd * Dd * sizeof(f16);       // Wt
    const size_t per_split = (size_t)Bb * Dd * Nn * sizeof(f16)  // Opart slice
                           + 2 * (size_t)Bb * Nn * sizeof(float);// m/l slice
    int split = (head + 4 * per_split <= ws_size) ? 4 : 2;

    f16* Qh    = (f16*)d_ws;
    f16* Kh    = Qh + (size_t)Bb * Nn * Dd;
    f16* Vth   = Kh + (size_t)Bb * Nn * Dd;
    f16* Wt    = Vth + (size_t)Bb * Nn * Dd;
    f16* Opart = Wt + (size_t)3 * Dd * Dd;
    float* mpart = (float*)(Opart + (size_t)split * Bb * Dd * Nn);
    float* lpart = mpart + (size_t)split * Bb * Nn;

    wtrans<<<dim3(16, 3), 256, 0, stream>>>(Wq, Wk, Wv, Wt);
    qkv_fused<<<dim3(Nn / 64, Bb), 512, 0, stream>>>(
        x, Wt, bq, bk, bv, Qh, Kh, Vth);
    attn_mfma<<<dim3(Nn / BQ, Bb, split), 256, 0, stream>>>(
        Qh, Kh, Vth, Opart, mpart, lpart, Nn / split);
    if (split == 4)
        combine<4><<<dim3(Nn / 2048, Dd, Bb), 256, 0, stream>>>(
            Opart, mpart, lpart, out);
    else
        combine<2><<<dim3(Nn / 2048, Dd, Bb), 256, 0, stream>>>(
            Opart, mpart, lpart, out);
}

// Round 4
// 210.464 us; speedup vs baseline: 1.6492x; 1.6492x over previous
//
#include <hip/hip_runtime.h>
#include <math.h>

#define Dd 256
#define Nn 4096
#define Bb 4
#define BQ 128      // q rows per attn block (8 waves x 16 in S phase)
#define BK 128      // kv rows per tile
#define SPLIT 2     // KV splits -> grid exactly 256 blocks = 1 round

typedef _Float16 f16;
typedef _Float16 half8 __attribute__((ext_vector_type(8)));
typedef _Float16 half4 __attribute__((ext_vector_type(4)));
typedef float f32x4 __attribute__((ext_vector_type(4)));

#define LOG2E 1.4426950408889634f

// DPP row_ror butterfly over 16-lane rows (VALU pipe, not LDS)
template <int CTRL>
__device__ __forceinline__ float dppf(float x) {
    int r = __builtin_amdgcn_update_dpp(0, __builtin_bit_cast(int, x),
                                        CTRL, 0xF, 0xF, false);
    return __builtin_bit_cast(float, r);
}
__device__ __forceinline__ float red16_max(float x) {
    x = fmaxf(x, dppf<0x128>(x));
    x = fmaxf(x, dppf<0x124>(x));
    x = fmaxf(x, dppf<0x122>(x));
    x = fmaxf(x, dppf<0x121>(x));
    return x;
}
__device__ __forceinline__ float red16_sum(float x) {
    x += dppf<0x128>(x); x += dppf<0x124>(x);
    x += dppf<0x122>(x); x += dppf<0x121>(x);
    return x;
}

// ---------------------------------------------------------------------------
// Kernel 0: W transpose+cast.  Wt[which][d'][d] = (f16) W[d][d']
// ---------------------------------------------------------------------------
__global__ __launch_bounds__(256) void wtrans(
    const float* __restrict__ Wq, const float* __restrict__ Wk,
    const float* __restrict__ Wv, f16* __restrict__ Wt)
{
    __shared__ float ld[64][65];
    const int which = blockIdx.y;
    const float* W = which == 0 ? Wq : (which == 1 ? Wk : Wv);
    const int tr = (blockIdx.x >> 2) * 64;
    const int tc = (blockIdx.x & 3) * 64;
    const int t = threadIdx.x;
    #pragma unroll
    for (int i = 0; i < 16; ++i) {
        int u = t + i * 256, r = u >> 6, c = u & 63;
        ld[r][c] = W[(size_t)(tr + r) * Dd + tc + c];
    }
    __syncthreads();
    f16* Wo = Wt + (size_t)which * Dd * Dd;
    #pragma unroll
    for (int i = 0; i < 16; ++i) {
        int u = t + i * 256, cp = u >> 6, rp = u & 63;
        Wo[(size_t)(tc + cp) * Dd + tr + rp] = (f16)ld[rp][cp];
    }
}

// ---------------------------------------------------------------------------
// Kernel 1: FUSED QKV projection via MFMA (unchanged R13 winner).
// ---------------------------------------------------------------------------
__global__ __launch_bounds__(512, 1) void qkv_fused(
    const float* __restrict__ x, const f16* __restrict__ Wt,
    const float* __restrict__ bq, const float* __restrict__ bk,
    const float* __restrict__ bv,
    f16* __restrict__ Qh, f16* __restrict__ Kh, f16* __restrict__ Vth)
{
    __shared__ __align__(16) f16 Ws[256][264];   // 135168 B; first 64 rows alias xT
    __shared__ float bs3[3][256];                //   3072 B
    f16 (*xT)[264] = (f16 (*)[264])&Ws[0][0];    // xT[64][264]

    const int t = threadIdx.x;
    const int wave = t >> 6, lane = t & 63, quad = lane >> 4, l15 = lane & 15;
    const int g = wave & 3;        // row group: rows 16g..16g+16
    const int h = wave >> 2;       // col half: d' in [128h, 128h+128)
    const int n0 = blockIdx.x * 64;
    const int b = blockIdx.y;

    if (t < 256) { bs3[0][t] = bq[t]; bs3[1][t] = bk[t]; bs3[2][t] = bv[t]; }

    // Stage xT[n][d] = (f16) x[b][d][n0+n]; 512 threads x 8 float4 reads
    const float* xb = x + (size_t)b * Dd * Nn;
    #pragma unroll
    for (int i = 0; i < 8; ++i) {
        int u = t + i * 512, d = u >> 4, nq = (u & 15) * 4;
        float4 v4 = *(const float4*)&xb[(size_t)d * Nn + n0 + nq];
        xT[nq + 0][d] = (f16)v4.x; xT[nq + 1][d] = (f16)v4.y;
        xT[nq + 2][d] = (f16)v4.z; xT[nq + 3][d] = (f16)v4.w;
    }
    __syncthreads();

    // Lift A-fragments to registers (xT is dead after this + barrier)
    half8 a[8];
    #pragma unroll
    for (int c = 0; c < 8; ++c)
        a[c] = *(const half8*)&xT[16 * g + l15][c * 32 + quad * 8];

    const int nrow = n0 + 16 * g + quad * 4;

    for (int which = 0; which < 3; ++which) {
        __syncthreads();   // A-frag reads (which=0) / prior MFMA reads done

        // Bulk-stage full W^T (256x256 halfs) from L2: 16 b128 per thread
        const f16* Wb = Wt + (size_t)which * Dd * Dd;
        #pragma unroll
        for (int i = 0; i < 16; ++i) {
            int u = t + i * 512;
            int r = u >> 5, c = u & 31;
            *(half8*)&Ws[r][c * 8] = *(const half8*)(Wb + (size_t)r * Dd + c * 8);
        }
        __syncthreads();

        // 64 MFMAs/wave, zero barriers: this wave's 8 col-tiles x 8 k-chunks
        f32x4 acc[8];
        #pragma unroll
        for (int dt = 0; dt < 8; ++dt) acc[dt] = (f32x4){0.f, 0.f, 0.f, 0.f};
        #pragma unroll
        for (int c = 0; c < 8; ++c) {
            #pragma unroll
            for (int dt = 0; dt < 8; ++dt) {
                half8 bfr = *(const half8*)&Ws[h * 128 + dt * 16 + l15][c * 32 + quad * 8];
                acc[dt] = __builtin_amdgcn_mfma_f32_16x16x32_f16(a[c], bfr, acc[dt], 0, 0, 0);
            }
        }

        // Epilogue
        if (which < 2) {
            f16* O = (which == 0 ? Qh : Kh) + ((size_t)b * Nn + nrow) * Dd;
            #pragma unroll
            for (int dt = 0; dt < 8; ++dt) {
                int col = h * 128 + dt * 16 + l15;
                float bvv = bs3[which][col];
                #pragma unroll
                for (int r = 0; r < 4; ++r)
                    O[(size_t)r * Dd + col] = (f16)(acc[dt][r] + bvv);
            }
        } else {
            f16* O = Vth + (size_t)b * Dd * Nn;
            #pragma unroll
            for (int dt = 0; dt < 8; ++dt) {
                int col = h * 128 + dt * 16 + l15;
                float bvv = bs3[2][col];
                half4 o;
                #pragma unroll
                for (int r = 0; r < 4; ++r) o[r] = (f16)(acc[dt][r] + bvv);
                *(half4*)&O[(size_t)col * Nn + nrow] = o;
            }
        }
    }
}

// ---------------------------------------------------------------------------
// Kernel 2: MFMA flash attention, R16 = R0 structure (BQ=BK=128, 8 waves,
// split=2) + T14 async-STAGE split with double-buffered K:
//   - next K tile's global loads ISSUE at tile top (into kreg[8]),
//   - ds_write into Ks[buf^1] happens AFTER PV (write-late),
// so the L2 latency of staging hides under S-MFMA + softmax + PV instead of
// sitting exposed between two barriers (R0's barrier A->loads->vmcnt(0)->
// ds_write->barrier B). Ps aliases the front of the CURRENT Ks buffer
// (dead after barrier B2); staging targets the OTHER buffer, so no clash.
// Barriers/tile stay at 3 (B2, C, D). LDS 2*67.6K + 1K = 136.2 KB.
// Reg peak ~212 unified (kreg +32) < 256 cap at 2 waves/SIMD: no spill.
// ---------------------------------------------------------------------------
__global__ __launch_bounds__(512, 2) void attn_mfma(
    const f16* __restrict__ Qh, const f16* __restrict__ Kh,
    const f16* __restrict__ Vth, f16* __restrict__ Opart,
    float* __restrict__ mpart, float* __restrict__ lpart)
{
    __shared__ __align__(16) f16 Ks[2][BK][264];  // 135168 B, double-buffered
    __shared__ float alpha_s[8][16];              //   512 B
    __shared__ float l_sh[8][16];                 //   512 B

    const int t    = threadIdx.x;
    const int wave = t >> 6, lane = t & 63;
    const int quad = lane >> 4, l15 = lane & 15;
    const int b    = blockIdx.y;
    const int s    = blockIdx.z;
    const int q0   = blockIdx.x * BQ;
    const int qw   = q0 + wave * 16;       // this wave's S-phase q rows
    const int kvlen = Nn / SPLIT;
    const int kv0  = s * kvlen;

    // Q A-fragments, pre-scaled by log2(e)
    half8 qf[8];
    const f16* Qrow = Qh + ((size_t)b * Nn + qw + l15) * Dd + quad * 8;
    #pragma unroll
    for (int c = 0; c < 8; ++c) {
        qf[c] = *(const half8*)(Qrow + c * 32);
        qf[c] = qf[c] * (f16)LOG2E;
    }

    // acc[qb*2+dt]: q-block qb (0..7), d-cols 32*wave + dt*16 + l15 (dt 0..1)
    f32x4 acc[16];
    #pragma unroll
    for (int n = 0; n < 16; ++n) acc[n] = (f32x4){0.f, 0.f, 0.f, 0.f};
    f32x4 m4 = {-1e30f, -1e30f, -1e30f, -1e30f};
    f32x4 l4 = {0.f, 0.f, 0.f, 0.f};

    const f16* Kb   = Kh + (size_t)b * Nn * Dd;
    const f16* Vrow = Vth + (size_t)b * Dd * Nn
                    + (size_t)(wave * 32 + l15) * Nn + quad * 8;

    // Prologue: stage first K tile into Ks[0] (exposed once per block)
    #pragma unroll
    for (int i = 0; i < 8; ++i) {
        int u = t + i * 512;
        int r = u >> 5, c = u & 31;
        *(half8*)&Ks[0][r][c * 8] =
            *(const half8*)(Kb + (size_t)(kv0 + r) * Dd + c * 8);
    }
    __syncthreads();

    int buf = 0;
    for (int k0 = kv0; k0 < kv0 + kvlen; k0 += BK) {
        // T14 issue-early: next K tile global loads -> registers. Consumed
        // (ds_write) only after PV, ~15K cycles later: latency fully hidden.
        const int kn = k0 + BK;
        const bool havenext = kn < kv0 + kvlen;   // block-uniform
        half8 kreg[8];
        if (havenext) {
            #pragma unroll
            for (int i = 0; i < 8; ++i) {
                int u = t + i * 512;
                int r = u >> 5, c = u & 31;
                kreg[i] = *(const half8*)(Kb + (size_t)(kn + r) * Dd + c * 8);
            }
        }

        // V loads for THIS tile: 2 d-tiles x 4 kv-quarters; consumed in PV
        half8 vbf[2][4];
        #pragma unroll
        for (int dt = 0; dt < 2; ++dt) {
            #pragma unroll
            for (int cbb = 0; cbb < 4; ++cbb)
                vbf[dt][cbb] = *(const half8*)(Vrow + (size_t)dt * 16 * Nn + k0 + cbb * 32);
        }

        // S = Q K^T (log2 domain) from Ks[buf], eight 16x16 col-blocks
        f32x4 S[8];
        #pragma unroll
        for (int cb = 0; cb < 8; ++cb) S[cb] = (f32x4){0.f, 0.f, 0.f, 0.f};
        #pragma unroll
        for (int c = 0; c < 8; ++c) {
            #pragma unroll
            for (int cb = 0; cb < 8; ++cb) {
                half8 kb = *(const half8*)&Ks[buf][cb * 16 + l15][c * 32 + quad * 8];
                S[cb] = __builtin_amdgcn_mfma_f32_16x16x32_f16(qf[c], kb, S[cb], 0, 0, 0);
            }
        }

        // Online softmax (exp2 domain), DPP reductions; P computed in-place
        f32x4 tmax = S[0];
        #pragma unroll
        for (int cb = 1; cb < 8; ++cb) {
            tmax.x = fmaxf(tmax.x, S[cb].x); tmax.y = fmaxf(tmax.y, S[cb].y);
            tmax.z = fmaxf(tmax.z, S[cb].z); tmax.w = fmaxf(tmax.w, S[cb].w);
        }
        tmax.x = red16_max(tmax.x); tmax.y = red16_max(tmax.y);
        tmax.z = red16_max(tmax.z); tmax.w = red16_max(tmax.w);
        f32x4 newm;
        newm.x = fmaxf(m4.x, tmax.x); newm.y = fmaxf(m4.y, tmax.y);
        newm.z = fmaxf(m4.z, tmax.z); newm.w = fmaxf(m4.w, tmax.w);
        f32x4 al;
        al.x = __builtin_amdgcn_exp2f(m4.x - newm.x);
        al.y = __builtin_amdgcn_exp2f(m4.y - newm.y);
        al.z = __builtin_amdgcn_exp2f(m4.z - newm.z);
        al.w = __builtin_amdgcn_exp2f(m4.w - newm.w);
        #pragma unroll
        for (int cb = 0; cb < 8; ++cb) {       // P overwrites S (reg saver)
            S[cb].x = __builtin_amdgcn_exp2f(S[cb].x - newm.x);
            S[cb].y = __builtin_amdgcn_exp2f(S[cb].y - newm.y);
            S[cb].z = __builtin_amdgcn_exp2f(S[cb].z - newm.z);
            S[cb].w = __builtin_amdgcn_exp2f(S[cb].w - newm.w);
        }
        f32x4 rsum = S[0];
        #pragma unroll
        for (int cb = 1; cb < 8; ++cb) rsum += S[cb];
        rsum.x = red16_sum(rsum.x); rsum.y = red16_sum(rsum.y);
        rsum.z = red16_sum(rsum.z); rsum.w = red16_sum(rsum.w);
        l4 = l4 * al + rsum;
        m4 = newm;

        __syncthreads();   // B2: every wave's S-phase reads of Ks[buf] done

        // Publish P (f16) and alpha into the alias of Ks[buf] (K tile dead)
        f16 (*Ps)[16][136] = (f16 (*)[16][136])&Ks[buf][0][0];
        const int pr = quad * 4;
        #pragma unroll
        for (int cb = 0; cb < 8; ++cb) {
            Ps[wave][pr + 0][cb * 16 + l15] = (f16)S[cb].x;
            Ps[wave][pr + 1][cb * 16 + l15] = (f16)S[cb].y;
            Ps[wave][pr + 2][cb * 16 + l15] = (f16)S[cb].z;
            Ps[wave][pr + 3][cb * 16 + l15] = (f16)S[cb].w;
        }
        if (l15 == 0) {
            float4 a4 = {al.x, al.y, al.z, al.w};
            *(float4*)&alpha_s[wave][pr] = a4;
        }
        __syncthreads();   // C: Ps/alpha visible

        // Rescale O by each q-block's alpha (skip when converged)
        float4 alq[8];
        int need = 0;
        #pragma unroll
        for (int qb = 0; qb < 8; ++qb) {
            alq[qb] = *(const float4*)&alpha_s[qb][pr];
            need |= (alq[qb].x != 1.f) | (alq[qb].y != 1.f) |
                    (alq[qb].z != 1.f) | (alq[qb].w != 1.f);
        }
        if (__any(need)) {
            #pragma unroll
            for (int qb = 0; qb < 8; ++qb) {
                f32x4 a = {alq[qb].x, alq[qb].y, alq[qb].z, alq[qb].w};
                acc[qb * 2 + 0] *= a;
                acc[qb * 2 + 1] *= a;
            }
        }

        // PV: 8 q-blocks x 2 d-tiles x 4 kv-quarters; A-frag one b128 each
        #pragma unroll
        for (int qb = 0; qb < 8; ++qb) {
            #pragma unroll
            for (int cbb = 0; cbb < 4; ++cbb) {
                half8 ap = *(const half8*)&Ps[qb][l15][cbb * 32 + quad * 8];
                acc[qb * 2 + 0] = __builtin_amdgcn_mfma_f32_16x16x32_f16(
                    ap, vbf[0][cbb], acc[qb * 2 + 0], 0, 0, 0);
                acc[qb * 2 + 1] = __builtin_amdgcn_mfma_f32_16x16x32_f16(
                    ap, vbf[1][cbb], acc[qb * 2 + 1], 0, 0, 0);
            }
        }

        // T14 write-late: commit prefetched K tile to the OTHER buffer.
        if (havenext) {
            #pragma unroll
            for (int i = 0; i < 8; ++i) {
                int u = t + i * 512;
                int r = u >> 5, c = u & 31;
                *(half8*)&Ks[buf ^ 1][r][c * 8] = kreg[i];
            }
            buf ^= 1;
        }
        __syncthreads();   // D: Ks[buf] ready for next tile's S phase
    }

    // Publish l, write m/l partials (this wave's own 16 q rows)
    if (l15 == 0) {
        const int pr = quad * 4;
        float4 lv = {l4.x, l4.y, l4.z, l4.w};
        *(float4*)&l_sh[wave][pr] = lv;
        float mv[4] = {m4.x, m4.y, m4.z, m4.w};
        float lvv[4] = {l4.x, l4.y, l4.z, l4.w};
        #pragma unroll
        for (int r = 0; r < 4; ++r) {
            int n = qw + pr + r;
            mpart[(size_t)(s * Bb + b) * Nn + n] = mv[r];
            lpart[(size_t)(s * Bb + b) * Nn + n] = lvv[r];
        }
    }
    __syncthreads();

    // Normalize + store partial O: 8 q-blocks x this wave's 2 d-tiles
    f16* Ob = Opart + (size_t)(s * Bb + b) * Dd * Nn;
    #pragma unroll
    for (int qb = 0; qb < 8; ++qb) {
        float4 lq = *(const float4*)&l_sh[qb][quad * 4];
        f32x4 inv = {1.f / lq.x, 1.f / lq.y, 1.f / lq.z, 1.f / lq.w};
        #pragma unroll
        for (int dt = 0; dt < 2; ++dt) {
            int d = wave * 32 + dt * 16 + l15;
            f32x4 o = acc[qb * 2 + dt] * inv;
            half4 oh;
            oh[0] = (f16)o.x; oh[1] = (f16)o.y; oh[2] = (f16)o.z; oh[3] = (f16)o.w;
            *(half4*)&Ob[(size_t)d * Nn + q0 + qb * 16 + quad * 4] = oh;
        }
    }
}

// ---------------------------------------------------------------------------
// Kernel 3: combine split partials (exp2 domain).
// ---------------------------------------------------------------------------
__global__ __launch_bounds__(256) void combine(
    const f16* __restrict__ Opart, const float* __restrict__ mpart,
    const float* __restrict__ lpart, float* __restrict__ out)
{
    const int t = threadIdx.x;
    const int n0 = (blockIdx.x * 256 + t) * 8;
    const int d = blockIdx.y, b = blockIdx.z;

    float m[SPLIT][8], l[SPLIT][8];
    #pragma unroll
    for (int s = 0; s < SPLIT; ++s) {
        size_t base = (size_t)(s * Bb + b) * Nn + n0;
        float4 a0 = *(const float4*)&mpart[base];
        float4 a1 = *(const float4*)&mpart[base + 4];
        float4 c0 = *(const float4*)&lpart[base];
        float4 c1 = *(const float4*)&lpart[base + 4];
        m[s][0]=a0.x; m[s][1]=a0.y; m[s][2]=a0.z; m[s][3]=a0.w;
        m[s][4]=a1.x; m[s][5]=a1.y; m[s][6]=a1.z; m[s][7]=a1.w;
        l[s][0]=c0.x; l[s][1]=c0.y; l[s][2]=c0.z; l[s][3]=c0.w;
        l[s][4]=c1.x; l[s][5]=c1.y; l[s][6]=c1.z; l[s][7]=c1.w;
    }
    float w[SPLIT][8];
    #pragma unroll
    for (int jx = 0; jx < 8; ++jx) {
        float M = m[0][jx];
        #pragma unroll
        for (int s = 1; s < SPLIT; ++s) M = fmaxf(M, m[s][jx]);
        float L = 0.f;
        #pragma unroll
        for (int s = 0; s < SPLIT; ++s) {
            float ws = l[s][jx] * __builtin_amdgcn_exp2f(m[s][jx] - M);
            w[s][jx] = ws; L += ws;
        }
        float invL = 1.f / L;
        #pragma unroll
        for (int s = 0; s < SPLIT; ++s) w[s][jx] *= invL;
    }

    float o[8];
    #pragma unroll
    for (int jx = 0; jx < 8; ++jx) o[jx] = 0.f;
    #pragma unroll
    for (int s = 0; s < SPLIT; ++s) {
        half8 h = *(const half8*)&Opart[((size_t)(s * Bb + b) * Dd + d) * Nn + n0];
        #pragma unroll
        for (int jx = 0; jx < 8; ++jx) o[jx] += w[s][jx] * (float)h[jx];
    }
    float* op = out + ((size_t)b * Dd + d) * Nn + n0;
    f32x4 o0 = {o[0], o[1], o[2], o[3]};
    f32x4 o1 = {o[4], o[5], o[6], o[7]};
    *(f32x4*)op = o0;
    *(f32x4*)(op + 4) = o1;
}

extern "C" void kernel_launch(void* const* d_in, const int* in_sizes, int n_in,
                              void* d_out, int out_size, void* d_ws, size_t ws_size,
                              hipStream_t stream) {
    const float* x  = (const float*)d_in[0];
    const float* Wq = (const float*)d_in[1];
    const float* bq = (const float*)d_in[2];
    const float* Wk = (const float*)d_in[3];
    const float* bk = (const float*)d_in[4];
    const float* Wv = (const float*)d_in[5];
    const float* bv = (const float*)d_in[6];
    float* out = (float*)d_out;

    f16* Qh    = (f16*)d_ws;
    f16* Kh    = Qh + (size_t)Bb * Nn * Dd;
    f16* Vth   = Kh + (size_t)Bb * Nn * Dd;
    f16* Wt    = Vth + (size_t)Bb * Nn * Dd;
    f16* Opart = Wt + (size_t)3 * Dd * Dd;
    float* mpart = (float*)(Opart + (size_t)SPLIT * Bb * Dd * Nn);
    float* lpart = mpart + (size_t)SPLIT * Bb * Nn;

    wtrans<<<dim3(16, 3), 256, 0, stream>>>(Wq, Wk, Wv, Wt);
    qkv_fused<<<dim3(Nn / 64, Bb), 512, 0, stream>>>(
        x, Wt, bq, bk, bv, Qh, Kh, Vth);
    attn_mfma<<<dim3(Nn / BQ, Bb, SPLIT), 512, 0, stream>>>(
        Qh, Kh, Vth, Opart, mpart, lpart);
    combine<<<dim3(Nn / 2048, Dd, Bb), 256, 0, stream>>>(
        Opart, mpart, lpart, out);
}

// Round 5
// 209.446 us; speedup vs baseline: 1.6572x; 1.0049x over previous
//
#include <hip/hip_runtime.h>
#include <math.h>

#define Dd 256
#define Nn 4096
#define Bb 4
#define BQ 128      // q rows per attn block (8 waves x 16 in S phase)
#define BK 128      // kv rows per tile
#define SPLIT 2     // KV splits -> grid exactly 256 blocks = 1 round

typedef _Float16 f16;
typedef _Float16 half8 __attribute__((ext_vector_type(8)));
typedef _Float16 half4 __attribute__((ext_vector_type(4)));
typedef float f32x4 __attribute__((ext_vector_type(4)));

#define LOG2E 1.4426950408889634f

// DPP row_ror butterfly over 16-lane rows (VALU pipe, not LDS)
template <int CTRL>
__device__ __forceinline__ float dppf(float x) {
    int r = __builtin_amdgcn_update_dpp(0, __builtin_bit_cast(int, x),
                                        CTRL, 0xF, 0xF, false);
    return __builtin_bit_cast(float, r);
}
__device__ __forceinline__ float red16_max(float x) {
    x = fmaxf(x, dppf<0x128>(x));
    x = fmaxf(x, dppf<0x124>(x));
    x = fmaxf(x, dppf<0x122>(x));
    x = fmaxf(x, dppf<0x121>(x));
    return x;
}
__device__ __forceinline__ float red16_sum(float x) {
    x += dppf<0x128>(x); x += dppf<0x124>(x);
    x += dppf<0x122>(x); x += dppf<0x121>(x);
    return x;
}

// ---------------------------------------------------------------------------
// Kernel 0: W transpose+cast.  Wt[which][d'][d] = (f16) W[d][d']
// ---------------------------------------------------------------------------
__global__ __launch_bounds__(256) void wtrans(
    const float* __restrict__ Wq, const float* __restrict__ Wk,
    const float* __restrict__ Wv, f16* __restrict__ Wt)
{
    __shared__ float ld[64][65];
    const int which = blockIdx.y;
    const float* W = which == 0 ? Wq : (which == 1 ? Wk : Wv);
    const int tr = (blockIdx.x >> 2) * 64;
    const int tc = (blockIdx.x & 3) * 64;
    const int t = threadIdx.x;
    #pragma unroll
    for (int i = 0; i < 16; ++i) {
        int u = t + i * 256, r = u >> 6, c = u & 63;
        ld[r][c] = W[(size_t)(tr + r) * Dd + tc + c];
    }
    __syncthreads();
    f16* Wo = Wt + (size_t)which * Dd * Dd;
    #pragma unroll
    for (int i = 0; i < 16; ++i) {
        int u = t + i * 256, cp = u >> 6, rp = u & 63;
        Wo[(size_t)(tc + cp) * Dd + tr + rp] = (f16)ld[rp][cp];
    }
}

// ---------------------------------------------------------------------------
// Kernel 1: QKV projection, R17 REWRITE. R13's version staged the FULL
// 256x256 W through LDS per 64-row block (384 KB LDS round-trip for 25
// MFLOP of MFMA) with 6 full-drain barriers at 1 block/CU. This version:
//   - W fragments live in REGISTERS (each wave owns 32 out-cols; 16 half8
//     = 64 VGPR per projection), loaded straight from L2/L3 Wt. No W in
//     LDS, no staging barriers.
//   - xT staged ONCE (33.8 KB), read-only after => exactly 1 barrier.
//   - 256-thread blocks, grid (Nn/64, 2 col-halves, Bb) = 512 blocks =
//     2 blocks/CU: independent blocks overlap staging and MFMA phases.
//   - x read twice total (once per col-half): +16.8 MB HBM, ~+2.7 us.
// which-loop fully unrolled so bias[] indexing is compile-time (no scratch).
// ---------------------------------------------------------------------------
__global__ __launch_bounds__(256) void qkv_fused(
    const float* __restrict__ x, const f16* __restrict__ Wt,
    const float* __restrict__ bq, const float* __restrict__ bk,
    const float* __restrict__ bv,
    f16* __restrict__ Qh, f16* __restrict__ Kh, f16* __restrict__ Vth)
{
    __shared__ __align__(16) f16 xT[64][264];   // 33792 B

    const int t = threadIdx.x;
    const int wave = t >> 6, lane = t & 63, quad = lane >> 4, l15 = lane & 15;
    const int n0  = blockIdx.x * 64;
    const int ch  = blockIdx.y;           // col half: [128*ch, 128*ch+128)
    const int b   = blockIdx.z;
    const int col0 = ch * 128 + wave * 32;  // this wave's 32 out-cols

    // Stage xT[n][d] = (f16) x[b][d][n0+n]; 256 threads x 16 float4 reads
    const float* xb = x + (size_t)b * Dd * Nn;
    #pragma unroll
    for (int i = 0; i < 16; ++i) {
        int u = t + i * 256, d = u >> 4, nq = (u & 15) * 4;
        float4 v4 = *(const float4*)&xb[(size_t)d * Nn + n0 + nq];
        xT[nq + 0][d] = (f16)v4.x; xT[nq + 1][d] = (f16)v4.y;
        xT[nq + 2][d] = (f16)v4.z; xT[nq + 3][d] = (f16)v4.w;
    }

    // Biases for this wave's two col-tiles (direct, no LDS)
    float bias[3][2];
    #pragma unroll
    for (int ct = 0; ct < 2; ++ct) {
        int col = col0 + ct * 16 + l15;
        bias[0][ct] = bq[col]; bias[1][ct] = bk[col]; bias[2][ct] = bv[col];
    }

    __syncthreads();   // the ONLY barrier: xT visible, read-only hereafter

    #pragma unroll
    for (int which = 0; which < 3; ++which) {
        // B-fragments from L2: 16 x b128 per wave, register-resident
        const f16* Wb = Wt + (size_t)which * Dd * Dd;
        half8 wf[2][8];
        #pragma unroll
        for (int ct = 0; ct < 2; ++ct)
            #pragma unroll
            for (int c = 0; c < 8; ++c)
                wf[ct][c] = *(const half8*)(Wb
                    + (size_t)(col0 + ct * 16 + l15) * Dd + c * 32 + quad * 8);

        // 64 rows x 32 cols per wave: 4 row-groups x 2 col-tiles x 8 chunks
        f32x4 acc[4][2];
        #pragma unroll
        for (int rg = 0; rg < 4; ++rg) {
            acc[rg][0] = (f32x4){0.f, 0.f, 0.f, 0.f};
            acc[rg][1] = (f32x4){0.f, 0.f, 0.f, 0.f};
        }
        #pragma unroll
        for (int rg = 0; rg < 4; ++rg) {
            #pragma unroll
            for (int c = 0; c < 8; ++c) {
                half8 a = *(const half8*)&xT[rg * 16 + l15][c * 32 + quad * 8];
                acc[rg][0] = __builtin_amdgcn_mfma_f32_16x16x32_f16(
                    a, wf[0][c], acc[rg][0], 0, 0, 0);
                acc[rg][1] = __builtin_amdgcn_mfma_f32_16x16x32_f16(
                    a, wf[1][c], acc[rg][1], 0, 0, 0);
            }
        }

        // Epilogue
        if (which < 2) {
            f16* O = (which == 0 ? Qh : Kh) + ((size_t)b * Nn + n0) * Dd;
            #pragma unroll
            for (int rg = 0; rg < 4; ++rg) {
                #pragma unroll
                for (int ct = 0; ct < 2; ++ct) {
                    int col = col0 + ct * 16 + l15;
                    float bvv = bias[which][ct];
                    #pragma unroll
                    for (int r = 0; r < 4; ++r)
                        O[(size_t)(rg * 16 + quad * 4 + r) * Dd + col] =
                            (f16)(acc[rg][ct][r] + bvv);
                }
            }
        } else {
            f16* O = Vth + (size_t)b * Dd * Nn;
            #pragma unroll
            for (int rg = 0; rg < 4; ++rg) {
                #pragma unroll
                for (int ct = 0; ct < 2; ++ct) {
                    int col = col0 + ct * 16 + l15;
                    float bvv = bias[2][ct];
                    half4 o;
                    #pragma unroll
                    for (int r = 0; r < 4; ++r) o[r] = (f16)(acc[rg][ct][r] + bvv);
                    *(half4*)&O[(size_t)col * Nn + n0 + rg * 16 + quad * 4] = o;
                }
            }
        }
    }
}

// ---------------------------------------------------------------------------
// Kernel 2: MFMA flash attention (byte-identical to the R4 winner).
// R0 structure (BQ=BK=128, 8 waves, split=2) + T14 async-STAGE split with
// double-buffered K. attn dispatch measured 120.7 us, MfmaUtil 23.
// ---------------------------------------------------------------------------
__global__ __launch_bounds__(512, 2) void attn_mfma(
    const f16* __restrict__ Qh, const f16* __restrict__ Kh,
    const f16* __restrict__ Vth, f16* __restrict__ Opart,
    float* __restrict__ mpart, float* __restrict__ lpart)
{
    __shared__ __align__(16) f16 Ks[2][BK][264];  // 135168 B, double-buffered
    __shared__ float alpha_s[8][16];              //   512 B
    __shared__ float l_sh[8][16];                 //   512 B

    const int t    = threadIdx.x;
    const int wave = t >> 6, lane = t & 63;
    const int quad = lane >> 4, l15 = lane & 15;
    const int b    = blockIdx.y;
    const int s    = blockIdx.z;
    const int q0   = blockIdx.x * BQ;
    const int qw   = q0 + wave * 16;       // this wave's S-phase q rows
    const int kvlen = Nn / SPLIT;
    const int kv0  = s * kvlen;

    // Q A-fragments, pre-scaled by log2(e)
    half8 qf[8];
    const f16* Qrow = Qh + ((size_t)b * Nn + qw + l15) * Dd + quad * 8;
    #pragma unroll
    for (int c = 0; c < 8; ++c) {
        qf[c] = *(const half8*)(Qrow + c * 32);
        qf[c] = qf[c] * (f16)LOG2E;
    }

    // acc[qb*2+dt]: q-block qb (0..7), d-cols 32*wave + dt*16 + l15 (dt 0..1)
    f32x4 acc[16];
    #pragma unroll
    for (int n = 0; n < 16; ++n) acc[n] = (f32x4){0.f, 0.f, 0.f, 0.f};
    f32x4 m4 = {-1e30f, -1e30f, -1e30f, -1e30f};
    f32x4 l4 = {0.f, 0.f, 0.f, 0.f};

    const f16* Kb   = Kh + (size_t)b * Nn * Dd;
    const f16* Vrow = Vth + (size_t)b * Dd * Nn
                    + (size_t)(wave * 32 + l15) * Nn + quad * 8;

    // Prologue: stage first K tile into Ks[0] (exposed once per block)
    #pragma unroll
    for (int i = 0; i < 8; ++i) {
        int u = t + i * 512;
        int r = u >> 5, c = u & 31;
        *(half8*)&Ks[0][r][c * 8] =
            *(const half8*)(Kb + (size_t)(kv0 + r) * Dd + c * 8);
    }
    __syncthreads();

    int buf = 0;
    for (int k0 = kv0; k0 < kv0 + kvlen; k0 += BK) {
        // T14 issue-early: next K tile global loads -> registers. Consumed
        // (ds_write) only after PV, ~15K cycles later: latency fully hidden.
        const int kn = k0 + BK;
        const bool havenext = kn < kv0 + kvlen;   // block-uniform
        half8 kreg[8];
        if (havenext) {
            #pragma unroll
            for (int i = 0; i < 8; ++i) {
                int u = t + i * 512;
                int r = u >> 5, c = u & 31;
                kreg[i] = *(const half8*)(Kb + (size_t)(kn + r) * Dd + c * 8);
            }
        }

        // V loads for THIS tile: 2 d-tiles x 4 kv-quarters; consumed in PV
        half8 vbf[2][4];
        #pragma unroll
        for (int dt = 0; dt < 2; ++dt) {
            #pragma unroll
            for (int cbb = 0; cbb < 4; ++cbb)
                vbf[dt][cbb] = *(const half8*)(Vrow + (size_t)dt * 16 * Nn + k0 + cbb * 32);
        }

        // S = Q K^T (log2 domain) from Ks[buf], eight 16x16 col-blocks
        f32x4 S[8];
        #pragma unroll
        for (int cb = 0; cb < 8; ++cb) S[cb] = (f32x4){0.f, 0.f, 0.f, 0.f};
        #pragma unroll
        for (int c = 0; c < 8; ++c) {
            #pragma unroll
            for (int cb = 0; cb < 8; ++cb) {
                half8 kb = *(const half8*)&Ks[buf][cb * 16 + l15][c * 32 + quad * 8];
                S[cb] = __builtin_amdgcn_mfma_f32_16x16x32_f16(qf[c], kb, S[cb], 0, 0, 0);
            }
        }

        // Online softmax (exp2 domain), DPP reductions; P computed in-place
        f32x4 tmax = S[0];
        #pragma unroll
        for (int cb = 1; cb < 8; ++cb) {
            tmax.x = fmaxf(tmax.x, S[cb].x); tmax.y = fmaxf(tmax.y, S[cb].y);
            tmax.z = fmaxf(tmax.z, S[cb].z); tmax.w = fmaxf(tmax.w, S[cb].w);
        }
        tmax.x = red16_max(tmax.x); tmax.y = red16_max(tmax.y);
        tmax.z = red16_max(tmax.z); tmax.w = red16_max(tmax.w);
        f32x4 newm;
        newm.x = fmaxf(m4.x, tmax.x); newm.y = fmaxf(m4.y, tmax.y);
        newm.z = fmaxf(m4.z, tmax.z); newm.w = fmaxf(m4.w, tmax.w);
        f32x4 al;
        al.x = __builtin_amdgcn_exp2f(m4.x - newm.x);
        al.y = __builtin_amdgcn_exp2f(m4.y - newm.y);
        al.z = __builtin_amdgcn_exp2f(m4.z - newm.z);
        al.w = __builtin_amdgcn_exp2f(m4.w - newm.w);
        #pragma unroll
        for (int cb = 0; cb < 8; ++cb) {       // P overwrites S (reg saver)
            S[cb].x = __builtin_amdgcn_exp2f(S[cb].x - newm.x);
            S[cb].y = __builtin_amdgcn_exp2f(S[cb].y - newm.y);
            S[cb].z = __builtin_amdgcn_exp2f(S[cb].z - newm.z);
            S[cb].w = __builtin_amdgcn_exp2f(S[cb].w - newm.w);
        }
        f32x4 rsum = S[0];
        #pragma unroll
        for (int cb = 1; cb < 8; ++cb) rsum += S[cb];
        rsum.x = red16_sum(rsum.x); rsum.y = red16_sum(rsum.y);
        rsum.z = red16_sum(rsum.z); rsum.w = red16_sum(rsum.w);
        l4 = l4 * al + rsum;
        m4 = newm;

        __syncthreads();   // B2: every wave's S-phase reads of Ks[buf] done

        // Publish P (f16) and alpha into the alias of Ks[buf] (K tile dead)
        f16 (*Ps)[16][136] = (f16 (*)[16][136])&Ks[buf][0][0];
        const int pr = quad * 4;
        #pragma unroll
        for (int cb = 0; cb < 8; ++cb) {
            Ps[wave][pr + 0][cb * 16 + l15] = (f16)S[cb].x;
            Ps[wave][pr + 1][cb * 16 + l15] = (f16)S[cb].y;
            Ps[wave][pr + 2][cb * 16 + l15] = (f16)S[cb].z;
            Ps[wave][pr + 3][cb * 16 + l15] = (f16)S[cb].w;
        }
        if (l15 == 0) {
            float4 a4 = {al.x, al.y, al.z, al.w};
            *(float4*)&alpha_s[wave][pr] = a4;
        }
        __syncthreads();   // C: Ps/alpha visible

        // Rescale O by each q-block's alpha (skip when converged)
        float4 alq[8];
        int need = 0;
        #pragma unroll
        for (int qb = 0; qb < 8; ++qb) {
            alq[qb] = *(const float4*)&alpha_s[qb][pr];
            need |= (alq[qb].x != 1.f) | (alq[qb].y != 1.f) |
                    (alq[qb].z != 1.f) | (alq[qb].w != 1.f);
        }
        if (__any(need)) {
            #pragma unroll
            for (int qb = 0; qb < 8; ++qb) {
                f32x4 a = {alq[qb].x, alq[qb].y, alq[qb].z, alq[qb].w};
                acc[qb * 2 + 0] *= a;
                acc[qb * 2 + 1] *= a;
            }
        }

        // PV: 8 q-blocks x 2 d-tiles x 4 kv-quarters; A-frag one b128 each
        #pragma unroll
        for (int qb = 0; qb < 8; ++qb) {
            #pragma unroll
            for (int cbb = 0; cbb < 4; ++cbb) {
                half8 ap = *(const half8*)&Ps[qb][l15][cbb * 32 + quad * 8];
                acc[qb * 2 + 0] = __builtin_amdgcn_mfma_f32_16x16x32_f16(
                    ap, vbf[0][cbb], acc[qb * 2 + 0], 0, 0, 0);
                acc[qb * 2 + 1] = __builtin_amdgcn_mfma_f32_16x16x32_f16(
                    ap, vbf[1][cbb], acc[qb * 2 + 1], 0, 0, 0);
            }
        }

        // T14 write-late: commit prefetched K tile to the OTHER buffer.
        if (havenext) {
            #pragma unroll
            for (int i = 0; i < 8; ++i) {
                int u = t + i * 512;
                int r = u >> 5, c = u & 31;
                *(half8*)&Ks[buf ^ 1][r][c * 8] = kreg[i];
            }
            buf ^= 1;
        }
        __syncthreads();   // D: Ks[buf] ready for next tile's S phase
    }

    // Publish l, write m/l partials (this wave's own 16 q rows)
    if (l15 == 0) {
        const int pr = quad * 4;
        float4 lv = {l4.x, l4.y, l4.z, l4.w};
        *(float4*)&l_sh[wave][pr] = lv;
        float mv[4] = {m4.x, m4.y, m4.z, m4.w};
        float lvv[4] = {l4.x, l4.y, l4.z, l4.w};
        #pragma unroll
        for (int r = 0; r < 4; ++r) {
            int n = qw + pr + r;
            mpart[(size_t)(s * Bb + b) * Nn + n] = mv[r];
            lpart[(size_t)(s * Bb + b) * Nn + n] = lvv[r];
        }
    }
    __syncthreads();

    // Normalize + store partial O: 8 q-blocks x this wave's 2 d-tiles
    f16* Ob = Opart + (size_t)(s * Bb + b) * Dd * Nn;
    #pragma unroll
    for (int qb = 0; qb < 8; ++qb) {
        float4 lq = *(const float4*)&l_sh[qb][quad * 4];
        f32x4 inv = {1.f / lq.x, 1.f / lq.y, 1.f / lq.z, 1.f / lq.w};
        #pragma unroll
        for (int dt = 0; dt < 2; ++dt) {
            int d = wave * 32 + dt * 16 + l15;
            f32x4 o = acc[qb * 2 + dt] * inv;
            half4 oh;
            oh[0] = (f16)o.x; oh[1] = (f16)o.y; oh[2] = (f16)o.z; oh[3] = (f16)o.w;
            *(half4*)&Ob[(size_t)d * Nn + q0 + qb * 16 + quad * 4] = oh;
        }
    }
}

// ---------------------------------------------------------------------------
// Kernel 3: combine split partials (exp2 domain).
// ---------------------------------------------------------------------------
__global__ __launch_bounds__(256) void combine(
    const f16* __restrict__ Opart, const float* __restrict__ mpart,
    const float* __restrict__ lpart, float* __restrict__ out)
{
    const int t = threadIdx.x;
    const int n0 = (blockIdx.x * 256 + t) * 8;
    const int d = blockIdx.y, b = blockIdx.z;

    float m[SPLIT][8], l[SPLIT][8];
    #pragma unroll
    for (int s = 0; s < SPLIT; ++s) {
        size_t base = (size_t)(s * Bb + b) * Nn + n0;
        float4 a0 = *(const float4*)&mpart[base];
        float4 a1 = *(const float4*)&mpart[base + 4];
        float4 c0 = *(const float4*)&lpart[base];
        float4 c1 = *(const float4*)&lpart[base + 4];
        m[s][0]=a0.x; m[s][1]=a0.y; m[s][2]=a0.z; m[s][3]=a0.w;
        m[s][4]=a1.x; m[s][5]=a1.y; m[s][6]=a1.z; m[s][7]=a1.w;
        l[s][0]=c0.x; l[s][1]=c0.y; l[s][2]=c0.z; l[s][3]=c0.w;
        l[s][4]=c1.x; l[s][5]=c1.y; l[s][6]=c1.z; l[s][7]=c1.w;
    }
    float w[SPLIT][8];
    #pragma unroll
    for (int jx = 0; jx < 8; ++jx) {
        float M = m[0][jx];
        #pragma unroll
        for (int s = 1; s < SPLIT; ++s) M = fmaxf(M, m[s][jx]);
        float L = 0.f;
        #pragma unroll
        for (int s = 0; s < SPLIT; ++s) {
            float ws = l[s][jx] * __builtin_amdgcn_exp2f(m[s][jx] - M);
            w[s][jx] = ws; L += ws;
        }
        float invL = 1.f / L;
        #pragma unroll
        for (int s = 0; s < SPLIT; ++s) w[s][jx] *= invL;
    }

    float o[8];
    #pragma unroll
    for (int jx = 0; jx < 8; ++jx) o[jx] = 0.f;
    #pragma unroll
    for (int s = 0; s < SPLIT; ++s) {
        half8 h = *(const half8*)&Opart[((size_t)(s * Bb + b) * Dd + d) * Nn + n0];
        #pragma unroll
        for (int jx = 0; jx < 8; ++jx) o[jx] += w[s][jx] * (float)h[jx];
    }
    float* op = out + ((size_t)b * Dd + d) * Nn + n0;
    f32x4 o0 = {o[0], o[1], o[2], o[3]};
    f32x4 o1 = {o[4], o[5], o[6], o[7]};
    *(f32x4*)op = o0;
    *(f32x4*)(op + 4) = o1;
}

extern "C" void kernel_launch(void* const* d_in, const int* in_sizes, int n_in,
                              void* d_out, int out_size, void* d_ws, size_t ws_size,
                              hipStream_t stream) {
    const float* x  = (const float*)d_in[0];
    const float* Wq = (const float*)d_in[1];
    const float* bq = (const float*)d_in[2];
    const float* Wk = (const float*)d_in[3];
    const float* bk = (const float*)d_in[4];
    const float* Wv = (const float*)d_in[5];
    const float* bv = (const float*)d_in[6];
    float* out = (float*)d_out;

    f16* Qh    = (f16*)d_ws;
    f16* Kh    = Qh + (size_t)Bb * Nn * Dd;
    f16* Vth   = Kh + (size_t)Bb * Nn * Dd;
    f16* Wt    = Vth + (size_t)Bb * Nn * Dd;
    f16* Opart = Wt + (size_t)3 * Dd * Dd;
    float* mpart = (float*)(Opart + (size_t)SPLIT * Bb * Dd * Nn);
    float* lpart = mpart + (size_t)SPLIT * Bb * Nn;

    wtrans<<<dim3(16, 3), 256, 0, stream>>>(Wq, Wk, Wv, Wt);
    qkv_fused<<<dim3(Nn / 64, 2, Bb), 256, 0, stream>>>(
        x, Wt, bq, bk, bv, Qh, Kh, Vth);
    attn_mfma<<<dim3(Nn / BQ, Bb, SPLIT), 512, 0, stream>>>(
        Qh, Kh, Vth, Opart, mpart, lpart);
    combine<<<dim3(Nn / 2048, Dd, Bb), 256, 0, stream>>>(
        Opart, mpart, lpart, out);
}